// Round 1
// baseline (1299.326 us; speedup 1.0000x reference)
//
#include <hip/hip_runtime.h>
#include <hip/hip_bf16.h>
#include <math.h>

// One wave (64 lanes) per sample; lane j handles light j (L == 64 == wavefront).
// Lane loads are stride-12B across the wave -> coalesced 768B regions.
// Sorted ray_indices -> same-address atomic runs ~122 deep, hidden behind ~900MB stream.
__global__ __launch_bounds__(256) void shade_kernel(
    const float* __restrict__ albedos,        // [N,3]
    const float* __restrict__ normals,        // [N,3]
    const float* __restrict__ light_dirs,     // [N,64,3]
    const float* __restrict__ light_cols,     // [N,64,3]
    const float* __restrict__ visibility,     // [N,64]
    const float* __restrict__ weights,        // [N]
    const int*   __restrict__ ray_indices,    // [N]
    float* __restrict__ acc,                  // [R*3] rgb accum, then [R] weight accum
    int N, int R)
{
    const int wave = (blockIdx.x * blockDim.x + threadIdx.x) >> 6;
    const int lane = threadIdx.x & 63;
    if (wave >= N) return;
    const int b = wave;

    // broadcast loads (same address across wave -> single fetch)
    const float nx = normals[b * 3 + 0];
    const float ny = normals[b * 3 + 1];
    const float nz = normals[b * 3 + 2];

    const int base = b * 192 + lane * 3;          // max 96e6, fits int32
    const float dx = light_dirs[base + 0];
    const float dy = light_dirs[base + 1];
    const float dz = light_dirs[base + 2];
    const float cr = light_cols[base + 0];
    const float cg = light_cols[base + 1];
    const float cb = light_cols[base + 2];
    const float v  = visibility[b * 64 + lane];

    const float dot = nx * dx + ny * dy + nz * dz;
    const unsigned long long mask = __ballot(dot > 0.0f);
    int count = __popcll(mask);
    if (count == 0) count = 1;
    const float inv = 1.0f / (float)count;

    float d = fminf(fmaxf(dot, 0.0f), 1.0f);
    const float s = d * inv * v;

    float sr = s * cr;
    float sg = s * cg;
    float sb = s * cb;

    // wave64 reduction
    #pragma unroll
    for (int off = 32; off > 0; off >>= 1) {
        sr += __shfl_down(sr, off, 64);
        sg += __shfl_down(sg, off, 64);
        sb += __shfl_down(sb, off, 64);
    }

    if (lane == 0) {
        const float w  = weights[b];
        const float ar = albedos[b * 3 + 0];
        const float ag = albedos[b * 3 + 1];
        const float ab = albedos[b * 3 + 2];
        const int   ri = ray_indices[b];
        atomicAdd(&acc[ri * 3 + 0], w * ar * sr);
        atomicAdd(&acc[ri * 3 + 1], w * ag * sg);
        atomicAdd(&acc[ri * 3 + 2], w * ab * sb);
        atomicAdd(&acc[R * 3 + ri], w);
    }
}

__global__ void finalize_kernel(
    const float* __restrict__ acc,   // [R*3] + [R]
    const float* __restrict__ bg,    // [R,3]
    float* __restrict__ out,         // [R,3]
    int R)
{
    const int c = blockIdx.x * blockDim.x + threadIdx.x;
    if (c >= R * 3) return;
    const int r = c / 3;
    const float aw = acc[R * 3 + r];
    const float x = acc[c] + bg[c] * (1.0f - aw);
    float y;
    if (x <= 0.0031308f) {
        y = 12.92f * x;
    } else {
        const float safe = fmaxf(x, 1e-8f);
        y = 1.055f * powf(safe, 1.0f / 2.4f) - 0.055f;
    }
    out[c] = y;
}

extern "C" void kernel_launch(void* const* d_in, const int* in_sizes, int n_in,
                              void* d_out, int out_size, void* d_ws, size_t ws_size,
                              hipStream_t stream) {
    const float* albedos     = (const float*)d_in[0];
    const float* normals     = (const float*)d_in[1];
    const float* light_dirs  = (const float*)d_in[2];
    const float* light_cols  = (const float*)d_in[3];
    const float* visibility  = (const float*)d_in[4];
    const float* bg          = (const float*)d_in[5];
    const float* weights     = (const float*)d_in[6];
    const int*   ray_indices = (const int*)d_in[7];
    // d_in[8] = num_rays scalar on device; recover R from background size instead.

    const int N = in_sizes[0] / 3;
    const int R = in_sizes[5] / 3;

    float* acc = (float*)d_ws;  // R*3 rgb + R weight accumulators

    hipMemsetAsync(acc, 0, (size_t)(R * 4) * sizeof(float), stream);

    // one wave per sample -> 4 samples per 256-thread block
    const int blocks = (N + 3) / 4;
    shade_kernel<<<blocks, 256, 0, stream>>>(albedos, normals, light_dirs, light_cols,
                                             visibility, weights, ray_indices, acc, N, R);

    const int fin_threads = R * 3;
    finalize_kernel<<<(fin_threads + 255) / 256, 256, 0, stream>>>(acc, bg, (float*)d_out, R);
}

// Round 2
// 1270.720 us; speedup vs baseline: 1.0225x; 1.0225x over previous
//
#include <hip/hip_runtime.h>
#include <hip/hip_bf16.h>
#include <math.h>

// Thread-per-sample: each thread streams its own contiguous 1792B
// (48 float4 dirs + 48 float4 cols + 16 float4 vis) and accumulates
// sum_j clip(dot_j)*vis_j*lc_j plus count(dot_j>0) in registers.
// count only scales the final sum, so a single pass suffices:
//   color = (albedo * w / count) * sum
// No shuffles, no ballot, no LDS. 28 float4 loads in flight per
// unroll-4 body -> latency fully hidden (R1 was bytes-in-flight bound).
__device__ __forceinline__ void accum_light(
    float nx, float ny, float nz,
    float dx, float dy, float dz,
    float cr, float cg, float cb,
    float v, float& sr, float& sg, float& sb, int& cnt)
{
    const float dot = nx * dx + ny * dy + nz * dz;
    cnt += (dot > 0.0f) ? 1 : 0;
    const float d = fminf(fmaxf(dot, 0.0f), 1.0f);
    const float s = d * v;
    sr = fmaf(s, cr, sr);
    sg = fmaf(s, cg, sg);
    sb = fmaf(s, cb, sb);
}

__global__ __launch_bounds__(256) void shade_kernel(
    const float*  __restrict__ albedos,      // [N,3]
    const float*  __restrict__ normals,      // [N,3]
    const float4* __restrict__ light_dirs,   // [N,48] float4 view of [N,64,3]
    const float4* __restrict__ light_cols,   // [N,48]
    const float4* __restrict__ visibility,   // [N,16] float4 view of [N,64]
    const float*  __restrict__ weights,      // [N]
    const int*    __restrict__ ray_indices,  // [N]
    float* __restrict__ acc,                 // [R*3] rgb accum + [R] weight accum
    int N, int R)
{
    const int b = blockIdx.x * blockDim.x + threadIdx.x;
    if (b >= N) return;

    const float nx = normals[b * 3 + 0];
    const float ny = normals[b * 3 + 1];
    const float nz = normals[b * 3 + 2];

    const float4* dirs = light_dirs + (size_t)b * 48;
    const float4* cols = light_cols + (size_t)b * 48;
    const float4* vis  = visibility + (size_t)b * 16;

    float sr = 0.f, sg = 0.f, sb = 0.f;
    int cnt = 0;

    #pragma unroll 4
    for (int it = 0; it < 16; ++it) {
        const float4 d0 = dirs[it * 3 + 0];
        const float4 d1 = dirs[it * 3 + 1];
        const float4 d2 = dirs[it * 3 + 2];
        const float4 c0 = cols[it * 3 + 0];
        const float4 c1 = cols[it * 3 + 1];
        const float4 c2 = cols[it * 3 + 2];
        const float4 v  = vis[it];
        // 4 lights packed in 3 float4s: light k uses floats [3k, 3k+2]
        accum_light(nx, ny, nz, d0.x, d0.y, d0.z, c0.x, c0.y, c0.z, v.x, sr, sg, sb, cnt);
        accum_light(nx, ny, nz, d0.w, d1.x, d1.y, c0.w, c1.x, c1.y, v.y, sr, sg, sb, cnt);
        accum_light(nx, ny, nz, d1.z, d1.w, d2.x, c1.z, c1.w, c2.x, v.z, sr, sg, sb, cnt);
        accum_light(nx, ny, nz, d2.y, d2.z, d2.w, c2.y, c2.z, c2.w, v.w, sr, sg, sb, cnt);
    }

    const float w   = weights[b];
    const float inv = w / (float)(cnt > 0 ? cnt : 1);
    const float ar  = albedos[b * 3 + 0];
    const float ag  = albedos[b * 3 + 1];
    const float ab  = albedos[b * 3 + 2];
    const int   ri  = ray_indices[b];

    // fire-and-forget device-scope atomics (no return value -> no wait)
    atomicAdd(&acc[ri * 3 + 0], ar * sr * inv);
    atomicAdd(&acc[ri * 3 + 1], ag * sg * inv);
    atomicAdd(&acc[ri * 3 + 2], ab * sb * inv);
    atomicAdd(&acc[R * 3 + ri], w);
}

__global__ void finalize_kernel(
    const float* __restrict__ acc,   // [R*3] + [R]
    const float* __restrict__ bg,    // [R,3]
    float* __restrict__ out,         // [R,3]
    int R)
{
    const int c = blockIdx.x * blockDim.x + threadIdx.x;
    if (c >= R * 3) return;
    const int r = c / 3;
    const float aw = acc[R * 3 + r];
    const float x = acc[c] + bg[c] * (1.0f - aw);
    float y;
    if (x <= 0.0031308f) {
        y = 12.92f * x;
    } else {
        const float safe = fmaxf(x, 1e-8f);
        y = 1.055f * powf(safe, 1.0f / 2.4f) - 0.055f;
    }
    out[c] = y;
}

extern "C" void kernel_launch(void* const* d_in, const int* in_sizes, int n_in,
                              void* d_out, int out_size, void* d_ws, size_t ws_size,
                              hipStream_t stream) {
    const float* albedos     = (const float*)d_in[0];
    const float* normals     = (const float*)d_in[1];
    const float4* light_dirs = (const float4*)d_in[2];
    const float4* light_cols = (const float4*)d_in[3];
    const float4* visibility = (const float4*)d_in[4];
    const float* bg          = (const float*)d_in[5];
    const float* weights     = (const float*)d_in[6];
    const int*   ray_indices = (const int*)d_in[7];

    const int N = in_sizes[0] / 3;
    const int R = in_sizes[5] / 3;

    float* acc = (float*)d_ws;  // R*3 rgb + R weight accumulators

    hipMemsetAsync(acc, 0, (size_t)(R * 4) * sizeof(float), stream);

    shade_kernel<<<(N + 255) / 256, 256, 0, stream>>>(
        albedos, normals, light_dirs, light_cols, visibility,
        weights, ray_indices, acc, N, R);

    const int fin_threads = R * 3;
    finalize_kernel<<<(fin_threads + 255) / 256, 256, 0, stream>>>(acc, bg, (float*)d_out, R);
}